// Round 7
// baseline (873.073 us; speedup 1.0000x reference)
//
#include <hip/hip_runtime.h>

#define TT 216
#define BB 16384
#define LOG2E 1.44269504088896340736f

typedef _Float16 h16;
typedef _Float16 half8 __attribute__((ext_vector_type(8)));
typedef _Float16 h4 __attribute__((ext_vector_type(4)));
typedef float f32x4 __attribute__((ext_vector_type(4)));
typedef int i2 __attribute__((ext_vector_type(2)));
typedef int i4 __attribute__((ext_vector_type(4)));
// Vector types get char-TBAA in clang (alias everything) -> safe for LDS type
// punning. Scalar puns (unsigned long long) carry their own TBAA tag and get
// reordered across _Float16 stores (round-2 bug) -- never use scalar puns.

__device__ __forceinline__ float rcp_f(float v) { return __builtin_amdgcn_rcpf(v); }
__device__ __forceinline__ float ex2(float v)   { return __builtin_amdgcn_exp2f(v); }

// Gate preactivations arrive PRE-SCALED: pi,pf,po = -log2e*(preact), pg = 2*log2e*(preact).
// State cs = 2*log2e * c (pre-scaled cell state).
// sigmoid(i) = 1/(1+2^pi); tanh(g) = (Eg-2)/Eg, Eg = 1+2^pg.
// cs' = cs/Ef + 2L*(Eg-2)/(Ei*Eg) -> single rcp via common denominator.
// h = (Ec-2)/(Eo*Ec), Ec = 1+2^min(cs',60)  (clamp: keeps Eo*Ec finite).
__device__ __forceinline__ float lstm_up(float pi, float pf, float pg, float po, float& cs)
{
    float ei = ex2(pi), ef = ex2(pf), eg = ex2(pg), eo = ex2(po);
    float Ei = 1.f + ei, Ef = 1.f + ef, Eg = 1.f + eg, Eo = 1.f + eo;
    float EiEg = Ei * Eg;
    float G = fmaf(2.f * LOG2E, Eg, -4.f * LOG2E);   // 2L*(Eg-2)
    float N = fmaf(cs, EiEg, Ef * G);
    cs = N * rcp_f(Ef * EiEg);
    float pc = fminf(cs, 60.f);
    float Ec = 1.f + ex2(pc);
    return (Ec - 2.f) * rcp_f(Eo * Ec);
}

// ---------------- weight prep ------------------------------------------------------------
// W1f/W1b: small-LSTM fragments as before.
// W2p: PERMUTED mid weights [16 m-tiles][16 rows][96 k] h16. m-tile p=4g+c, row m=q*4+r
// maps to original gate g, unit u = (c>=2?32:0)+(c&1)*4+8q+r. This permutation makes the
// MFMA C layout (row=q*4+r per tile) line up so each lane's lstm_up outputs ARE the next
// step's B-fragment elements: nf1[j]=unit 8q+j, nf2[j]=unit 32+8q+j -- no exchange at all.
// k: 0..31 = Wih_m cols (hs_f|hs_b), 32..95 = Whh_m cols (h2 unit = k-32).
// bzp: per-row pre-scaled bias f32 [16][16] (same permutation).
__global__ void prep_kernel(
    const float* __restrict__ Wih_f, const float* __restrict__ Whh_f,
    const float* __restrict__ bih_f, const float* __restrict__ bhh_f,
    const float* __restrict__ Wih_b, const float* __restrict__ Whh_b,
    const float* __restrict__ bih_b, const float* __restrict__ bhh_b,
    const float* __restrict__ Wih_m, const float* __restrict__ Whh_m,
    const float* __restrict__ bih_m, const float* __restrict__ bhh_m,
    h16* __restrict__ W1f, h16* __restrict__ W1b,
    h16* __restrict__ W2p, float* __restrict__ bzp)
{
    int gtid = blockIdx.x * blockDim.x + threadIdx.x;
    int gs = gridDim.x * blockDim.x;
    // small LSTMs: W1[n=64][k=32]: k<8 x, 8..23 h, 24 bias (X col24==1), 25..31 zero
    for (int idx = gtid; idx < 64 * 32; idx += gs) {
        int n = idx >> 5, k = idx & 31;
        float a = ((n >> 4) == 2) ? 2.f * LOG2E : -LOG2E;
        float vf = 0.f, vb = 0.f;
        if (k < 8)        { vf = Wih_f[n * 8 + k];       vb = Wih_b[n * 8 + k]; }
        else if (k < 24)  { vf = Whh_f[n * 16 + k - 8];  vb = Whh_b[n * 16 + k - 8]; }
        else if (k == 24) { vf = bih_f[n] + bhh_f[n];    vb = bih_b[n] + bhh_b[n]; }
        W1f[idx] = (h16)(vf * a);
        W1b[idx] = (h16)(vb * a);
    }
    // mid: permuted W2p [pm=256][k=96]
    for (int idx = gtid; idx < 256 * 96; idx += gs) {
        int pm = idx / 96, k = idx - pm * 96;
        int p = pm >> 4, m = pm & 15;
        int g = p >> 2, c = p & 3, qq = m >> 2, r = m & 3;
        int u = ((c >= 2) ? 32 : 0) + (c & 1) * 4 + 8 * qq + r;
        int n = g * 64 + u;
        float a = (g == 2) ? 2.f * LOG2E : -LOG2E;
        float v = (k < 32) ? Wih_m[n * 32 + k] : Whh_m[n * 64 + (k - 32)];
        W2p[idx] = (h16)(v * a);
    }
    // mid bias (pre-scaled, f32)
    for (int pm = gtid; pm < 256; pm += gs) {
        int p = pm >> 4, m = pm & 15;
        int g = p >> 2, c = p & 3, qq = m >> 2, r = m & 3;
        int u = ((c >= 2) ? 32 : 0) + (c & 1) * 4 + 8 * qq + r;
        int n = g * 64 + u;
        float a = (g == 2) ? 2.f * LOG2E : -LOG2E;
        bzp[pm] = (bih_m[n] + bhh_m[n]) * a;
    }
}

// ---------------- small LSTMs (fwd + bwd): ONE WAVE owns one (dir, 16-batch) recurrence ---
// v5 (kept): SWAPPED-OPERAND MFMA kills the LDS round-trip. z_g = mfma(A=W_g, B=state):
// lane(q,b) holds units q*4+r of batch b; next step's B-frag needs only a lane^16
// ds_swizzle pair. No LDS array, no barrier, no asm fence.
__global__ __launch_bounds__(256, 2) void small_lstm_kernel(
    const float* __restrict__ x,
    const float* __restrict__ h0f, const float* __restrict__ c0f,
    const float* __restrict__ h0b, const float* __restrict__ c0b,
    const h16* __restrict__ W1f, const h16* __restrict__ W1b,
    h16* __restrict__ hsf, h16* __restrict__ hsb)
{
    const int tid = threadIdx.x;
    const int wv = tid >> 6, lane = tid & 63;
    const int b = lane & 15, q = lane >> 4;

    const int wgid = blockIdx.x * 4 + wv;        // 2048 waves
    const int dir  = wgid & 1;
    const int base = (wgid >> 1) * 16;

    const float* h0 = dir ? h0b : h0f;
    const float* c0 = dir ? c0b : c0f;
    const h16* W1   = dir ? W1b : W1f;
    h16* hs = dir ? hsb : hsf;

    half8 wf0 = *(const half8*)(W1 + (0 * 16 + b) * 32 + q * 8);
    half8 wf1 = *(const half8*)(W1 + (1 * 16 + b) * 32 + q * 8);
    half8 wf2 = *(const half8*)(W1 + (2 * 16 + b) * 32 + q * 8);
    half8 wf3 = *(const half8*)(W1 + (3 * 16 + b) * 32 + q * 8);

    f32x4 cv = *(const f32x4*)(c0 + (size_t)(base + b) * 16 + q * 4);
    float cs0 = cv[0] * (2.f * LOG2E);
    float cs1 = cv[1] * (2.f * LOG2E);
    float cs2 = cv[2] * (2.f * LOG2E);
    float cs3 = cv[3] * (2.f * LOG2E);

    const int t0 = dir ? (TT - 1) : 0;

    half8 sf;
    if (q == 0) {
        const float* xp = x + ((size_t)t0 * BB + base + b) * 8;
        f32x4 u0 = *(const f32x4*)xp, u1 = *(const f32x4*)(xp + 4);
        sf[0] = (h16)u0[0]; sf[1] = (h16)u0[1]; sf[2] = (h16)u0[2]; sf[3] = (h16)u0[3];
        sf[4] = (h16)u1[0]; sf[5] = (h16)u1[1]; sf[6] = (h16)u1[2]; sf[7] = (h16)u1[3];
    } else if (q == 3) {
        sf[0] = (h16)1.f;
        sf[1] = (h16)0.f; sf[2] = (h16)0.f; sf[3] = (h16)0.f;
        sf[4] = (h16)0.f; sf[5] = (h16)0.f; sf[6] = (h16)0.f; sf[7] = (h16)0.f;
    } else {
        const float* hp = h0 + (size_t)(base + b) * 16 + (q - 1) * 8;
        f32x4 u0 = *(const f32x4*)hp, u1 = *(const f32x4*)(hp + 4);
        sf[0] = (h16)u0[0]; sf[1] = (h16)u0[1]; sf[2] = (h16)u0[2]; sf[3] = (h16)u0[3];
        sf[4] = (h16)u1[0]; sf[5] = (h16)u1[1]; sf[6] = (h16)u1[2]; sf[7] = (h16)u1[3];
    }

    // 4-slot x prefetch file (indices static under the 4x unroll -- rule #20)
    f32x4 xr[4][2];
    if (q == 0) {
#pragma unroll
        for (int u = 1; u <= 3; ++u) {
            int tl = dir ? (TT - 1 - u) : u;
            const float* xp = x + ((size_t)tl * BB + base + b) * 8;
            xr[u][0] = *(const f32x4*)xp;
            xr[u][1] = *(const f32x4*)(xp + 4);
        }
    }

    for (int it = 0; it < TT / 4; ++it) {        // 54 outer iters x 4 steps
#pragma unroll
        for (int j = 0; j < 4; ++j) {
            const int s = it * 4 + j;
            const int t = dir ? (TT - 1 - s) : s;

            f32x4 z0 = {0.f, 0.f, 0.f, 0.f}, z1 = z0, z2 = z0, z3 = z0;
            z0 = __builtin_amdgcn_mfma_f32_16x16x32_f16(wf0, sf, z0, 0, 0, 0);
            z1 = __builtin_amdgcn_mfma_f32_16x16x32_f16(wf1, sf, z1, 0, 0, 0);
            z2 = __builtin_amdgcn_mfma_f32_16x16x32_f16(wf2, sf, z2, 0, 0, 0);
            z3 = __builtin_amdgcn_mfma_f32_16x16x32_f16(wf3, sf, z3, 0, 0, 0);

            half8 xh;
            {
                const f32x4 u0 = xr[(j + 1) & 3][0], u1 = xr[(j + 1) & 3][1];
                xh[0] = (h16)u0[0]; xh[1] = (h16)u0[1]; xh[2] = (h16)u0[2]; xh[3] = (h16)u0[3];
                xh[4] = (h16)u1[0]; xh[5] = (h16)u1[1]; xh[6] = (h16)u1[2]; xh[7] = (h16)u1[3];
            }
            if (q == 0) {
                int ut = (s + 4 < TT) ? (s + 4) : (TT - 1);
                int tl = dir ? (TT - 1 - ut) : ut;
                const float* xp = x + ((size_t)tl * BB + base + b) * 8;
                xr[j][0] = *(const f32x4*)xp;
                xr[j][1] = *(const f32x4*)(xp + 4);
            }

            float hh0 = lstm_up(z0[0], z1[0], z2[0], z3[0], cs0);
            float hh1 = lstm_up(z0[1], z1[1], z2[1], z3[1], cs1);
            float hh2 = lstm_up(z0[2], z1[2], z2[2], z3[2], cs2);
            float hh3 = lstm_up(z0[3], z1[3], z2[3], z3[3], cs3);

            h4 hv;
            hv[0] = (h16)hh0; hv[1] = (h16)hh1; hv[2] = (h16)hh2; hv[3] = (h16)hh3;
            *(h4*)(hs + ((size_t)t * BB + base + b) * 16 + q * 4) = hv;

            i2 pk = __builtin_bit_cast(i2, hv);
            int sp0 = __builtin_amdgcn_ds_swizzle(pk[0], 0x401F);   // lane ^ 16
            int sp1 = __builtin_amdgcn_ds_swizzle(pk[1], 0x401F);

            i4 nw;
            nw[0] = (q == 1) ? sp0 : pk[0];
            nw[1] = (q == 1) ? sp1 : pk[1];
            nw[2] = (q == 1) ? pk[0] : sp0;
            nw[3] = (q == 1) ? pk[1] : sp1;
            half8 nf = __builtin_bit_cast(half8, nw);

            if (q == 0)      sf = xh;
            else if (q != 3) sf = nf;    // q==3 keeps its constant bias column
        }
    }
}

// ---------------- middle LSTM + dense: ONE WAVE owns the whole 16-batch window ----------
// v3: barrier-free. Per step, one wave computes ALL 256 gate-units x 16 batches:
// 16 m-tiles (p=4g+c, W2 rows permuted by prep) x 3 k-tiles = 48 MFMA, bias as MFMA
// C-init, 16 lstm_up/lane (grouped by c: 4 unit-blocks of 4), and thanks to the row
// permutation the packed h2 values ARE the next step's B-fragments (nf1: unit 8q+j,
// nf2: unit 32+8q+j) -- no LDS, no barriers, no cross-lane ops.
// kt=0 input (hs_f|hs_b) loads straight from global per lane (h16, no cvt), 4-step
// rotating prefetch. Dense out(t) = 2 MFMAs on the fresh nf frags; out stored as f32x4
// every 4 steps from q==0 lanes. 1024 waves = 1 wave/SIMD, issue-saturated (~1500
// VALU-cyc/step: 112 trans + ~200 VALU + 50 MFMA).
__global__ __launch_bounds__(256, 1) void mid_lstm_kernel(
    const h16* __restrict__ hsf, const h16* __restrict__ hsb,
    const float* __restrict__ h0m, const float* __restrict__ c0m,
    const h16* __restrict__ W2p, const float* __restrict__ bzp,
    const float* __restrict__ Wd, const float* __restrict__ bdp,
    float* __restrict__ out)
{
    const int tid = threadIdx.x;
    const int wv = tid >> 6, lane = tid & 63;
    const int b = lane & 15, q = lane >> 4;

    const int wgid = blockIdx.x * 4 + wv;        // 1024 waves = 1024 windows
    const int base = wgid * 16;

    // weights: A-frag of m-tile p, k-tile kt: lane(q,b) = W2p[row p*16+b][kt*32+q*8+j]
    half8 wfr[16][3];
#pragma unroll
    for (int p = 0; p < 16; ++p)
#pragma unroll
        for (int kt = 0; kt < 3; ++kt)
            wfr[p][kt] = *(const half8*)(W2p + (size_t)(p * 16 + b) * 96 + kt * 32 + q * 8);
    // bias C-init: lane(q,b) elem r = bias of row p*16+q*4+r (same addr across b -> bcast)
    f32x4 bz[16];
#pragma unroll
    for (int p = 0; p < 16; ++p)
        bz[p] = *(const f32x4*)(bzp + p * 16 + q * 4);
    // dense A-frags (row 0 = wd, permuted layout is identity: unit = k)
    half8 df1, df2;
#pragma unroll
    for (int j = 0; j < 8; ++j) {
        df1[j] = (b == 0) ? (h16)Wd[q * 8 + j] : (h16)0.f;
        df2[j] = (b == 0) ? (h16)Wd[32 + q * 8 + j] : (h16)0.f;
    }
    const float bdv = bdp[0];

    // cell state: cs[c][r] = c0m[base+b][u(c,q,r)], u = (c>=2?32:0)+(c&1)*4+8q+r
    f32x4 cs[4];
#pragma unroll
    for (int c = 0; c < 4; ++c) {
        int off = ((c >= 2) ? 32 : 0) + (c & 1) * 4 + 8 * q;
        f32x4 v = *(const f32x4*)(c0m + (size_t)(base + b) * 64 + off);
        cs[c][0] = v[0] * (2.f * LOG2E); cs[c][1] = v[1] * (2.f * LOG2E);
        cs[c][2] = v[2] * (2.f * LOG2E); cs[c][3] = v[3] * (2.f * LOG2E);
    }

    // initial h2 B-frags from h0m: nf1[j] = h0m[b][q*8+j], nf2[j] = h0m[b][32+q*8+j]
    half8 nf1, nf2;
    {
        const float* hp = h0m + (size_t)(base + b) * 64 + q * 8;
        f32x4 a0 = *(const f32x4*)hp, a1 = *(const f32x4*)(hp + 4);
        f32x4 a2 = *(const f32x4*)(hp + 32), a3 = *(const f32x4*)(hp + 36);
        nf1[0] = (h16)a0[0]; nf1[1] = (h16)a0[1]; nf1[2] = (h16)a0[2]; nf1[3] = (h16)a0[3];
        nf1[4] = (h16)a1[0]; nf1[5] = (h16)a1[1]; nf1[6] = (h16)a1[2]; nf1[7] = (h16)a1[3];
        nf2[0] = (h16)a2[0]; nf2[1] = (h16)a2[1]; nf2[2] = (h16)a2[2]; nf2[3] = (h16)a2[3];
        nf2[4] = (h16)a3[0]; nf2[5] = (h16)a3[1]; nf2[6] = (h16)a3[2]; nf2[7] = (h16)a3[3];
    }

    // hs prefetch: lane(q,b) kt=0 element j = (q<2 ? hs_f : hs_b)[t][base+b][(q&1)*8+j]
    const h16* hsq = (q < 2) ? hsf : hsb;
    const size_t hoff = (size_t)(base + b) * 16 + (q & 1) * 8;
    uint4 hx[4];
#pragma unroll
    for (int u = 0; u < 4; ++u)
        hx[u] = *(const uint4*)(hsq + (size_t)u * BB * 16 + hoff);

    f32x4 ot;
    for (int it = 0; it < TT / 4; ++it) {        // 54 outer iters x 4 steps
#pragma unroll
        for (int j = 0; j < 4; ++j) {
            const int s = it * 4 + j;
            const half8 sf0 = __builtin_bit_cast(half8, hx[j]);   // hs(s)

            h4 pkc[4];
#pragma unroll
            for (int c = 0; c < 4; ++c) {
                f32x4 z0 = bz[0 * 4 + c], z1 = bz[1 * 4 + c];
                f32x4 z2 = bz[2 * 4 + c], z3 = bz[3 * 4 + c];
                z0 = __builtin_amdgcn_mfma_f32_16x16x32_f16(wfr[0 * 4 + c][0], sf0, z0, 0, 0, 0);
                z0 = __builtin_amdgcn_mfma_f32_16x16x32_f16(wfr[0 * 4 + c][1], nf1, z0, 0, 0, 0);
                z0 = __builtin_amdgcn_mfma_f32_16x16x32_f16(wfr[0 * 4 + c][2], nf2, z0, 0, 0, 0);
                z1 = __builtin_amdgcn_mfma_f32_16x16x32_f16(wfr[1 * 4 + c][0], sf0, z1, 0, 0, 0);
                z1 = __builtin_amdgcn_mfma_f32_16x16x32_f16(wfr[1 * 4 + c][1], nf1, z1, 0, 0, 0);
                z1 = __builtin_amdgcn_mfma_f32_16x16x32_f16(wfr[1 * 4 + c][2], nf2, z1, 0, 0, 0);
                z2 = __builtin_amdgcn_mfma_f32_16x16x32_f16(wfr[2 * 4 + c][0], sf0, z2, 0, 0, 0);
                z2 = __builtin_amdgcn_mfma_f32_16x16x32_f16(wfr[2 * 4 + c][1], nf1, z2, 0, 0, 0);
                z2 = __builtin_amdgcn_mfma_f32_16x16x32_f16(wfr[2 * 4 + c][2], nf2, z2, 0, 0, 0);
                z3 = __builtin_amdgcn_mfma_f32_16x16x32_f16(wfr[3 * 4 + c][0], sf0, z3, 0, 0, 0);
                z3 = __builtin_amdgcn_mfma_f32_16x16x32_f16(wfr[3 * 4 + c][1], nf1, z3, 0, 0, 0);
                z3 = __builtin_amdgcn_mfma_f32_16x16x32_f16(wfr[3 * 4 + c][2], nf2, z3, 0, 0, 0);

                float c0v = cs[c][0];
                float hh0 = lstm_up(z0[0], z1[0], z2[0], z3[0], c0v); cs[c][0] = c0v;
                float c1v = cs[c][1];
                float hh1 = lstm_up(z0[1], z1[1], z2[1], z3[1], c1v); cs[c][1] = c1v;
                float c2v = cs[c][2];
                float hh2 = lstm_up(z0[2], z1[2], z2[2], z3[2], c2v); cs[c][2] = c2v;
                float c3v = cs[c][3];
                float hh3 = lstm_up(z0[3], z1[3], z2[3], z3[3], c3v); cs[c][3] = c3v;

                h4 pk;
                pk[0] = (h16)hh0; pk[1] = (h16)hh1; pk[2] = (h16)hh2; pk[3] = (h16)hh3;
                pkc[c] = pk;
            }
            // rebuild h2 B-frags (permutation makes this a plain concat)
            {
                i2 p0 = __builtin_bit_cast(i2, pkc[0]), p1 = __builtin_bit_cast(i2, pkc[1]);
                i2 p2 = __builtin_bit_cast(i2, pkc[2]), p3 = __builtin_bit_cast(i2, pkc[3]);
                i4 n1, n2;
                n1[0] = p0[0]; n1[1] = p0[1]; n1[2] = p1[0]; n1[3] = p1[1];
                n2[0] = p2[0]; n2[1] = p2[1]; n2[2] = p3[0]; n2[3] = p3[1];
                nf1 = __builtin_bit_cast(half8, n1);
                nf2 = __builtin_bit_cast(half8, n2);
            }
            // refill hs slot j for step s+4
            {
                int sl = (s + 4 < TT) ? (s + 4) : (TT - 1);
                hx[j] = *(const uint4*)(hsq + (size_t)sl * BB * 16 + hoff);
            }
            // dense: out(s) = wd . h2(s) + bd  (D row 0 -> q==0 lanes, elem 0)
            {
                f32x4 zd = {0.f, 0.f, 0.f, 0.f};
                zd = __builtin_amdgcn_mfma_f32_16x16x32_f16(df1, nf1, zd, 0, 0, 0);
                zd = __builtin_amdgcn_mfma_f32_16x16x32_f16(df2, nf2, zd, 0, 0, 0);
                ot[j] = zd[0] + bdv;
            }
        }
        if (q == 0)
            *(f32x4*)(out + (size_t)(base + b) * TT + it * 4) = ot;
    }
}

extern "C" void kernel_launch(void* const* d_in, const int* in_sizes, int n_in,
                              void* d_out, int out_size, void* d_ws, size_t ws_size,
                              hipStream_t stream)
{
    const float* x     = (const float*)d_in[0];
    const float* h0f   = (const float*)d_in[1];
    const float* c0f   = (const float*)d_in[2];
    const float* h0b   = (const float*)d_in[3];
    const float* c0b   = (const float*)d_in[4];
    const float* h0m   = (const float*)d_in[5];
    const float* c0m   = (const float*)d_in[6];
    const float* Wih_f = (const float*)d_in[7];
    const float* Whh_f = (const float*)d_in[8];
    const float* bih_f = (const float*)d_in[9];
    const float* bhh_f = (const float*)d_in[10];
    const float* Wih_b = (const float*)d_in[11];
    const float* Whh_b = (const float*)d_in[12];
    const float* bih_b = (const float*)d_in[13];
    const float* bhh_b = (const float*)d_in[14];
    const float* Wih_m = (const float*)d_in[15];
    const float* Whh_m = (const float*)d_in[16];
    const float* bih_m = (const float*)d_in[17];
    const float* bhh_m = (const float*)d_in[18];
    const float* Wd    = (const float*)d_in[19];
    const float* bd    = (const float*)d_in[20];

    char* ws = (char*)d_ws;
    h16*   W1f = (h16*)(ws + 0);         // 64*32*2   = 4096
    h16*   W1b = (h16*)(ws + 4096);      // 4096
    h16*   W2p = (h16*)(ws + 8192);      // 256*96*2  = 49152
    float* bzp = (float*)(ws + 57344);   // 256*4     = 1024
    h16*   hsf = (h16*)(ws + 65536);                               // [T][B][16] fp16
    h16*   hsb = (h16*)(ws + 65536 + (size_t)TT * BB * 16 * 2);    // [T][B][16] fp16

    prep_kernel<<<64, 256, 0, stream>>>(Wih_f, Whh_f, bih_f, bhh_f,
                                        Wih_b, Whh_b, bih_b, bhh_b,
                                        Wih_m, Whh_m, bih_m, bhh_m,
                                        W1f, W1b, W2p, bzp);
    small_lstm_kernel<<<512, 256, 0, stream>>>(x, h0f, c0f, h0b, c0b,
                                               W1f, W1b, hsf, hsb);
    mid_lstm_kernel<<<256, 256, 0, stream>>>(hsf, hsb, h0m, c0m, W2p, bzp,
                                             Wd, bd, (float*)d_out);
}

// Round 8
// 564.612 us; speedup vs baseline: 1.5463x; 1.5463x over previous
//
#include <hip/hip_runtime.h>

#define TT 216
#define BB 16384
#define LOG2E 1.44269504088896340736f

typedef _Float16 h16;
typedef _Float16 half8 __attribute__((ext_vector_type(8)));
typedef _Float16 h4 __attribute__((ext_vector_type(4)));
typedef float f32x4 __attribute__((ext_vector_type(4)));
typedef int i2 __attribute__((ext_vector_type(2)));
typedef int i4 __attribute__((ext_vector_type(4)));
// Vector types get char-TBAA in clang (alias everything) -> safe for LDS type
// punning. Scalar puns (unsigned long long) carry their own TBAA tag and get
// reordered across _Float16 stores (round-2 bug) -- never use scalar puns.

__device__ __forceinline__ float rcp_f(float v) { return __builtin_amdgcn_rcpf(v); }
__device__ __forceinline__ float ex2(float v)   { return __builtin_amdgcn_exp2f(v); }

// Gate preactivations arrive PRE-SCALED: pi,pf,po = -log2e*(preact), pg = 2*log2e*(preact).
// State cs = 2*log2e * c (pre-scaled cell state).
// sigmoid(i) = 1/(1+2^pi); tanh(g) = (Eg-2)/Eg, Eg = 1+2^pg.
// cs' = cs/Ef + 2L*(Eg-2)/(Ei*Eg) -> single rcp via common denominator.
// h = (Ec-2)/(Eo*Ec), Ec = 1+2^min(cs',60)  (clamp: keeps Eo*Ec finite).
__device__ __forceinline__ float lstm_up(float pi, float pf, float pg, float po, float& cs)
{
    float ei = ex2(pi), ef = ex2(pf), eg = ex2(pg), eo = ex2(po);
    float Ei = 1.f + ei, Ef = 1.f + ef, Eg = 1.f + eg, Eo = 1.f + eo;
    float EiEg = Ei * Eg;
    float G = fmaf(2.f * LOG2E, Eg, -4.f * LOG2E);   // 2L*(Eg-2)
    float N = fmaf(cs, EiEg, Ef * G);
    cs = N * rcp_f(Ef * EiEg);
    float pc = fminf(cs, 60.f);
    float Ec = 1.f + ex2(pc);
    return (Ec - 2.f) * rcp_f(Eo * Ec);
}

// ---------------- weight prep ------------------------------------------------------------
// W1f/W1b: small-LSTM fragments as before.
// W2p: PERMUTED mid weights [16 m-tiles][16 rows][96 k] h16. m-tile p=4g+c, row m=q*4+r
// maps to original gate g, unit u = (c>=2?32:0)+(c&1)*4+8q+r. This permutation makes the
// MFMA C layout (row=q*4+r per tile) line up so each lane's lstm_up outputs ARE the next
// step's B-fragment elements: nf1[j]=unit 8q+j, nf2[j]=unit 32+8q+j.
// (Layout correctness HW-verified in round 7 -- v3 passed, only spilled.)
// k: 0..31 = Wih_m cols (hs_f|hs_b), 32..95 = Whh_m cols (h2 unit = k-32).
// bzp: per-row pre-scaled bias f32 [16][16] (same permutation).
__global__ void prep_kernel(
    const float* __restrict__ Wih_f, const float* __restrict__ Whh_f,
    const float* __restrict__ bih_f, const float* __restrict__ bhh_f,
    const float* __restrict__ Wih_b, const float* __restrict__ Whh_b,
    const float* __restrict__ bih_b, const float* __restrict__ bhh_b,
    const float* __restrict__ Wih_m, const float* __restrict__ Whh_m,
    const float* __restrict__ bih_m, const float* __restrict__ bhh_m,
    h16* __restrict__ W1f, h16* __restrict__ W1b,
    h16* __restrict__ W2p, float* __restrict__ bzp)
{
    int gtid = blockIdx.x * blockDim.x + threadIdx.x;
    int gs = gridDim.x * blockDim.x;
    // small LSTMs: W1[n=64][k=32]: k<8 x, 8..23 h, 24 bias (X col24==1), 25..31 zero
    for (int idx = gtid; idx < 64 * 32; idx += gs) {
        int n = idx >> 5, k = idx & 31;
        float a = ((n >> 4) == 2) ? 2.f * LOG2E : -LOG2E;
        float vf = 0.f, vb = 0.f;
        if (k < 8)        { vf = Wih_f[n * 8 + k];       vb = Wih_b[n * 8 + k]; }
        else if (k < 24)  { vf = Whh_f[n * 16 + k - 8];  vb = Whh_b[n * 16 + k - 8]; }
        else if (k == 24) { vf = bih_f[n] + bhh_f[n];    vb = bih_b[n] + bhh_b[n]; }
        W1f[idx] = (h16)(vf * a);
        W1b[idx] = (h16)(vb * a);
    }
    // mid: permuted W2p [pm=256][k=96]
    for (int idx = gtid; idx < 256 * 96; idx += gs) {
        int pm = idx / 96, k = idx - pm * 96;
        int p = pm >> 4, m = pm & 15;
        int g = p >> 2, c = p & 3, qq = m >> 2, r = m & 3;
        int u = ((c >= 2) ? 32 : 0) + (c & 1) * 4 + 8 * qq + r;
        int n = g * 64 + u;
        float a = (g == 2) ? 2.f * LOG2E : -LOG2E;
        float v = (k < 32) ? Wih_m[n * 32 + k] : Whh_m[n * 64 + (k - 32)];
        W2p[idx] = (h16)(v * a);
    }
    // mid bias (pre-scaled, f32)
    for (int pm = gtid; pm < 256; pm += gs) {
        int p = pm >> 4, m = pm & 15;
        int g = p >> 2, c = p & 3, qq = m >> 2, r = m & 3;
        int u = ((c >= 2) ? 32 : 0) + (c & 1) * 4 + 8 * qq + r;
        int n = g * 64 + u;
        float a = (g == 2) ? 2.f * LOG2E : -LOG2E;
        bzp[pm] = (bih_m[n] + bhh_m[n]) * a;
    }
}

// ---------------- small LSTMs (fwd + bwd): ONE WAVE owns one (dir, 16-batch) recurrence ---
// v5 (kept): SWAPPED-OPERAND MFMA kills the LDS round-trip. z_g = mfma(A=W_g, B=state):
// lane(q,b) holds units q*4+r of batch b; next step's B-frag needs only a lane^16
// ds_swizzle pair. No LDS array, no barrier, no asm fence.
__global__ __launch_bounds__(256, 2) void small_lstm_kernel(
    const float* __restrict__ x,
    const float* __restrict__ h0f, const float* __restrict__ c0f,
    const float* __restrict__ h0b, const float* __restrict__ c0b,
    const h16* __restrict__ W1f, const h16* __restrict__ W1b,
    h16* __restrict__ hsf, h16* __restrict__ hsb)
{
    const int tid = threadIdx.x;
    const int wv = tid >> 6, lane = tid & 63;
    const int b = lane & 15, q = lane >> 4;

    const int wgid = blockIdx.x * 4 + wv;        // 2048 waves
    const int dir  = wgid & 1;
    const int base = (wgid >> 1) * 16;

    const float* h0 = dir ? h0b : h0f;
    const float* c0 = dir ? c0b : c0f;
    const h16* W1   = dir ? W1b : W1f;
    h16* hs = dir ? hsb : hsf;

    half8 wf0 = *(const half8*)(W1 + (0 * 16 + b) * 32 + q * 8);
    half8 wf1 = *(const half8*)(W1 + (1 * 16 + b) * 32 + q * 8);
    half8 wf2 = *(const half8*)(W1 + (2 * 16 + b) * 32 + q * 8);
    half8 wf3 = *(const half8*)(W1 + (3 * 16 + b) * 32 + q * 8);

    f32x4 cv = *(const f32x4*)(c0 + (size_t)(base + b) * 16 + q * 4);
    float cs0 = cv[0] * (2.f * LOG2E);
    float cs1 = cv[1] * (2.f * LOG2E);
    float cs2 = cv[2] * (2.f * LOG2E);
    float cs3 = cv[3] * (2.f * LOG2E);

    const int t0 = dir ? (TT - 1) : 0;

    half8 sf;
    if (q == 0) {
        const float* xp = x + ((size_t)t0 * BB + base + b) * 8;
        f32x4 u0 = *(const f32x4*)xp, u1 = *(const f32x4*)(xp + 4);
        sf[0] = (h16)u0[0]; sf[1] = (h16)u0[1]; sf[2] = (h16)u0[2]; sf[3] = (h16)u0[3];
        sf[4] = (h16)u1[0]; sf[5] = (h16)u1[1]; sf[6] = (h16)u1[2]; sf[7] = (h16)u1[3];
    } else if (q == 3) {
        sf[0] = (h16)1.f;
        sf[1] = (h16)0.f; sf[2] = (h16)0.f; sf[3] = (h16)0.f;
        sf[4] = (h16)0.f; sf[5] = (h16)0.f; sf[6] = (h16)0.f; sf[7] = (h16)0.f;
    } else {
        const float* hp = h0 + (size_t)(base + b) * 16 + (q - 1) * 8;
        f32x4 u0 = *(const f32x4*)hp, u1 = *(const f32x4*)(hp + 4);
        sf[0] = (h16)u0[0]; sf[1] = (h16)u0[1]; sf[2] = (h16)u0[2]; sf[3] = (h16)u0[3];
        sf[4] = (h16)u1[0]; sf[5] = (h16)u1[1]; sf[6] = (h16)u1[2]; sf[7] = (h16)u1[3];
    }

    // 4-slot x prefetch file (indices static under the 4x unroll -- rule #20)
    f32x4 xr[4][2];
    if (q == 0) {
#pragma unroll
        for (int u = 1; u <= 3; ++u) {
            int tl = dir ? (TT - 1 - u) : u;
            const float* xp = x + ((size_t)tl * BB + base + b) * 8;
            xr[u][0] = *(const f32x4*)xp;
            xr[u][1] = *(const f32x4*)(xp + 4);
        }
    }

    for (int it = 0; it < TT / 4; ++it) {        // 54 outer iters x 4 steps
#pragma unroll
        for (int j = 0; j < 4; ++j) {
            const int s = it * 4 + j;
            const int t = dir ? (TT - 1 - s) : s;

            f32x4 z0 = {0.f, 0.f, 0.f, 0.f}, z1 = z0, z2 = z0, z3 = z0;
            z0 = __builtin_amdgcn_mfma_f32_16x16x32_f16(wf0, sf, z0, 0, 0, 0);
            z1 = __builtin_amdgcn_mfma_f32_16x16x32_f16(wf1, sf, z1, 0, 0, 0);
            z2 = __builtin_amdgcn_mfma_f32_16x16x32_f16(wf2, sf, z2, 0, 0, 0);
            z3 = __builtin_amdgcn_mfma_f32_16x16x32_f16(wf3, sf, z3, 0, 0, 0);

            half8 xh;
            {
                const f32x4 u0 = xr[(j + 1) & 3][0], u1 = xr[(j + 1) & 3][1];
                xh[0] = (h16)u0[0]; xh[1] = (h16)u0[1]; xh[2] = (h16)u0[2]; xh[3] = (h16)u0[3];
                xh[4] = (h16)u1[0]; xh[5] = (h16)u1[1]; xh[6] = (h16)u1[2]; xh[7] = (h16)u1[3];
            }
            if (q == 0) {
                int ut = (s + 4 < TT) ? (s + 4) : (TT - 1);
                int tl = dir ? (TT - 1 - ut) : ut;
                const float* xp = x + ((size_t)tl * BB + base + b) * 8;
                xr[j][0] = *(const f32x4*)xp;
                xr[j][1] = *(const f32x4*)(xp + 4);
            }

            float hh0 = lstm_up(z0[0], z1[0], z2[0], z3[0], cs0);
            float hh1 = lstm_up(z0[1], z1[1], z2[1], z3[1], cs1);
            float hh2 = lstm_up(z0[2], z1[2], z2[2], z3[2], cs2);
            float hh3 = lstm_up(z0[3], z1[3], z2[3], z3[3], cs3);

            h4 hv;
            hv[0] = (h16)hh0; hv[1] = (h16)hh1; hv[2] = (h16)hh2; hv[3] = (h16)hh3;
            *(h4*)(hs + ((size_t)t * BB + base + b) * 16 + q * 4) = hv;

            i2 pk = __builtin_bit_cast(i2, hv);
            int sp0 = __builtin_amdgcn_ds_swizzle(pk[0], 0x401F);   // lane ^ 16
            int sp1 = __builtin_amdgcn_ds_swizzle(pk[1], 0x401F);

            i4 nw;
            nw[0] = (q == 1) ? sp0 : pk[0];
            nw[1] = (q == 1) ? sp1 : pk[1];
            nw[2] = (q == 1) ? pk[0] : sp0;
            nw[3] = (q == 1) ? pk[1] : sp1;
            half8 nf = __builtin_bit_cast(half8, nw);

            if (q == 0)      sf = xh;
            else if (q != 3) sf = nf;    // q==3 keeps its constant bias column
        }
    }
}

// ---------------- middle LSTM + dense: 2-WAVE PAIR owns one 16-batch window -------------
// v4: fixes v3's register spills (VGPR demand 380 > 256 arch cap -> 1.9GB scratch traffic)
// by splitting the 16 m-tiles across a wave pair. Role ro=0: c-blocks {0,1} (produces
// nf1 = units 8q+j); ro=1: c-blocks {2,3} (produces nf2 = units 32+8q+j). Per wave:
// 8 m-tiles x 3 kt = 96 weight VGPRs (+32 bz +8 cs +16 hx + working ~ 210 total, fits).
// Halves exchanged via double-buffered LDS (4KB) + ONE __syncthreads per step between
// exactly 2 waves (128-thread block = minimal barrier domain; parity buffer s&1 makes a
// single barrier WAR-safe). 24 MFMA + 8 lstm_up per wave-step. Dense on ro==1 (has both
// nf frags post-exchange). 1024 blocks x 2 waves = 8 waves/CU.
__global__ __launch_bounds__(128, 2) void mid_lstm_kernel(
    const h16* __restrict__ hsf, const h16* __restrict__ hsb,
    const float* __restrict__ h0m, const float* __restrict__ c0m,
    const h16* __restrict__ W2p, const float* __restrict__ bzp,
    const float* __restrict__ Wd, const float* __restrict__ bdp,
    float* __restrict__ out)
{
    __shared__ __attribute__((aligned(16))) uint4 xch[2][2][64];   // [buf][role][lane]

    const int tid = threadIdx.x;
    const int ro = tid >> 6, lane = tid & 63;
    const int b = lane & 15, q = lane >> 4;
    const int base = blockIdx.x * 16;

    // weights: this role's 8 m-tiles p = 4g + ro*2 + cc
    half8 wfr[4][2][3];
    f32x4 bz[4][2];
#pragma unroll
    for (int g = 0; g < 4; ++g)
#pragma unroll
        for (int cc = 0; cc < 2; ++cc) {
            int p = 4 * g + ro * 2 + cc;
#pragma unroll
            for (int kt = 0; kt < 3; ++kt)
                wfr[g][cc][kt] = *(const half8*)(W2p + (size_t)(p * 16 + b) * 96 + kt * 32 + q * 8);
            bz[g][cc] = *(const f32x4*)(bzp + p * 16 + q * 4);
        }
    // dense A-frags (consumed by ro==1; row 0 = wd, permuted layout is identity: unit = k)
    half8 df1, df2;
#pragma unroll
    for (int j = 0; j < 8; ++j) {
        df1[j] = (b == 0) ? (h16)Wd[q * 8 + j] : (h16)0.f;
        df2[j] = (b == 0) ? (h16)Wd[32 + q * 8 + j] : (h16)0.f;
    }
    const float bdv = bdp[0];

    // cell state: cs[cc][r] = c0m[base+b][ro*32 + cc*4 + 8q + r]
    f32x4 cs[2];
#pragma unroll
    for (int cc = 0; cc < 2; ++cc) {
        f32x4 v = *(const f32x4*)(c0m + (size_t)(base + b) * 64 + ro * 32 + cc * 4 + 8 * q);
        cs[cc][0] = v[0] * (2.f * LOG2E); cs[cc][1] = v[1] * (2.f * LOG2E);
        cs[cc][2] = v[2] * (2.f * LOG2E); cs[cc][3] = v[3] * (2.f * LOG2E);
    }

    // initial h2 B-frags from h0m (both waves hold both)
    half8 nf1, nf2;
    {
        const float* hp = h0m + (size_t)(base + b) * 64 + q * 8;
        f32x4 a0 = *(const f32x4*)hp, a1 = *(const f32x4*)(hp + 4);
        f32x4 a2 = *(const f32x4*)(hp + 32), a3 = *(const f32x4*)(hp + 36);
        nf1[0] = (h16)a0[0]; nf1[1] = (h16)a0[1]; nf1[2] = (h16)a0[2]; nf1[3] = (h16)a0[3];
        nf1[4] = (h16)a1[0]; nf1[5] = (h16)a1[1]; nf1[6] = (h16)a1[2]; nf1[7] = (h16)a1[3];
        nf2[0] = (h16)a2[0]; nf2[1] = (h16)a2[1]; nf2[2] = (h16)a2[2]; nf2[3] = (h16)a2[3];
        nf2[4] = (h16)a3[0]; nf2[5] = (h16)a3[1]; nf2[6] = (h16)a3[2]; nf2[7] = (h16)a3[3];
    }

    // hs prefetch: lane(q,b) kt=0 element j = (q<2 ? hs_f : hs_b)[t][base+b][(q&1)*8+j]
    const h16* hsq = (q < 2) ? hsf : hsb;
    const size_t hoff = (size_t)(base + b) * 16 + (q & 1) * 8;
    uint4 hx[4];
#pragma unroll
    for (int u = 0; u < 4; ++u)
        hx[u] = *(const uint4*)(hsq + (size_t)u * BB * 16 + hoff);

    f32x4 ot;
    for (int it = 0; it < TT / 4; ++it) {        // 54 outer iters x 4 steps
#pragma unroll
        for (int j = 0; j < 4; ++j) {
            const int s = it * 4 + j;
            const half8 sf0 = __builtin_bit_cast(half8, hx[j]);   // hs(s)

            h4 pkc[2];
#pragma unroll
            for (int cc = 0; cc < 2; ++cc) {
                f32x4 z0 = bz[0][cc], z1 = bz[1][cc], z2 = bz[2][cc], z3 = bz[3][cc];
                z0 = __builtin_amdgcn_mfma_f32_16x16x32_f16(wfr[0][cc][0], sf0, z0, 0, 0, 0);
                z0 = __builtin_amdgcn_mfma_f32_16x16x32_f16(wfr[0][cc][1], nf1, z0, 0, 0, 0);
                z0 = __builtin_amdgcn_mfma_f32_16x16x32_f16(wfr[0][cc][2], nf2, z0, 0, 0, 0);
                z1 = __builtin_amdgcn_mfma_f32_16x16x32_f16(wfr[1][cc][0], sf0, z1, 0, 0, 0);
                z1 = __builtin_amdgcn_mfma_f32_16x16x32_f16(wfr[1][cc][1], nf1, z1, 0, 0, 0);
                z1 = __builtin_amdgcn_mfma_f32_16x16x32_f16(wfr[1][cc][2], nf2, z1, 0, 0, 0);
                z2 = __builtin_amdgcn_mfma_f32_16x16x32_f16(wfr[2][cc][0], sf0, z2, 0, 0, 0);
                z2 = __builtin_amdgcn_mfma_f32_16x16x32_f16(wfr[2][cc][1], nf1, z2, 0, 0, 0);
                z2 = __builtin_amdgcn_mfma_f32_16x16x32_f16(wfr[2][cc][2], nf2, z2, 0, 0, 0);
                z3 = __builtin_amdgcn_mfma_f32_16x16x32_f16(wfr[3][cc][0], sf0, z3, 0, 0, 0);
                z3 = __builtin_amdgcn_mfma_f32_16x16x32_f16(wfr[3][cc][1], nf1, z3, 0, 0, 0);
                z3 = __builtin_amdgcn_mfma_f32_16x16x32_f16(wfr[3][cc][2], nf2, z3, 0, 0, 0);

                float c0v = cs[cc][0];
                float hh0 = lstm_up(z0[0], z1[0], z2[0], z3[0], c0v); cs[cc][0] = c0v;
                float c1v = cs[cc][1];
                float hh1 = lstm_up(z0[1], z1[1], z2[1], z3[1], c1v); cs[cc][1] = c1v;
                float c2v = cs[cc][2];
                float hh2 = lstm_up(z0[2], z1[2], z2[2], z3[2], c2v); cs[cc][2] = c2v;
                float c3v = cs[cc][3];
                float hh3 = lstm_up(z0[3], z1[3], z2[3], z3[3], c3v); cs[cc][3] = c3v;

                h4 pk;
                pk[0] = (h16)hh0; pk[1] = (h16)hh1; pk[2] = (h16)hh2; pk[3] = (h16)hh3;
                pkc[cc] = pk;
            }
            // my half-fragment (ro=0 -> nf1, ro=1 -> nf2)
            half8 mfh;
            {
                i2 p0 = __builtin_bit_cast(i2, pkc[0]), p1 = __builtin_bit_cast(i2, pkc[1]);
                i4 n;
                n[0] = p0[0]; n[1] = p0[1]; n[2] = p1[0]; n[3] = p1[1];
                mfh = __builtin_bit_cast(half8, n);
            }
            // exchange with partner wave (double-buffered, one barrier)
            xch[j & 1][ro][lane] = __builtin_bit_cast(uint4, mfh);
            // refill hs slot j for step s+4 (in flight across the barrier)
            {
                int sl = (s + 4 < TT) ? (s + 4) : (TT - 1);
                hx[j] = *(const uint4*)(hsq + (size_t)sl * BB * 16 + hoff);
            }
            __syncthreads();
            half8 poh = __builtin_bit_cast(half8, xch[j & 1][ro ^ 1][lane]);
            nf1 = ro ? poh : mfh;
            nf2 = ro ? mfh : poh;

            // dense: out(s) = wd . h2(s) + bd  (ro==1 wave; D row 0 -> q==0 lanes, elem 0)
            if (ro) {
                f32x4 zd = {0.f, 0.f, 0.f, 0.f};
                zd = __builtin_amdgcn_mfma_f32_16x16x32_f16(df1, nf1, zd, 0, 0, 0);
                zd = __builtin_amdgcn_mfma_f32_16x16x32_f16(df2, nf2, zd, 0, 0, 0);
                ot[j] = zd[0] + bdv;
            }
        }
        if (ro && q == 0)
            *(f32x4*)(out + (size_t)(base + b) * TT + it * 4) = ot;
    }
}

extern "C" void kernel_launch(void* const* d_in, const int* in_sizes, int n_in,
                              void* d_out, int out_size, void* d_ws, size_t ws_size,
                              hipStream_t stream)
{
    const float* x     = (const float*)d_in[0];
    const float* h0f   = (const float*)d_in[1];
    const float* c0f   = (const float*)d_in[2];
    const float* h0b   = (const float*)d_in[3];
    const float* c0b   = (const float*)d_in[4];
    const float* h0m   = (const float*)d_in[5];
    const float* c0m   = (const float*)d_in[6];
    const float* Wih_f = (const float*)d_in[7];
    const float* Whh_f = (const float*)d_in[8];
    const float* bih_f = (const float*)d_in[9];
    const float* bhh_f = (const float*)d_in[10];
    const float* Wih_b = (const float*)d_in[11];
    const float* Whh_b = (const float*)d_in[12];
    const float* bih_b = (const float*)d_in[13];
    const float* bhh_b = (const float*)d_in[14];
    const float* Wih_m = (const float*)d_in[15];
    const float* Whh_m = (const float*)d_in[16];
    const float* bih_m = (const float*)d_in[17];
    const float* bhh_m = (const float*)d_in[18];
    const float* Wd    = (const float*)d_in[19];
    const float* bd    = (const float*)d_in[20];

    char* ws = (char*)d_ws;
    h16*   W1f = (h16*)(ws + 0);         // 64*32*2   = 4096
    h16*   W1b = (h16*)(ws + 4096);      // 4096
    h16*   W2p = (h16*)(ws + 8192);      // 256*96*2  = 49152
    float* bzp = (float*)(ws + 57344);   // 256*4     = 1024
    h16*   hsf = (h16*)(ws + 65536);                               // [T][B][16] fp16
    h16*   hsb = (h16*)(ws + 65536 + (size_t)TT * BB * 16 * 2);    // [T][B][16] fp16

    prep_kernel<<<64, 256, 0, stream>>>(Wih_f, Whh_f, bih_f, bhh_f,
                                        Wih_b, Whh_b, bih_b, bhh_b,
                                        Wih_m, Whh_m, bih_m, bhh_m,
                                        W1f, W1b, W2p, bzp);
    small_lstm_kernel<<<512, 256, 0, stream>>>(x, h0f, c0f, h0b, c0b,
                                               W1f, W1b, hsf, hsb);
    mid_lstm_kernel<<<1024, 128, 0, stream>>>(hsf, hsb, h0m, c0m, W2p, bzp,
                                              Wd, bd, (float*)d_out);
}

// Round 9
// 545.910 us; speedup vs baseline: 1.5993x; 1.0343x over previous
//
#include <hip/hip_runtime.h>

#define TT 216
#define BB 16384
#define LOG2E 1.44269504088896340736f

typedef _Float16 h16;
typedef _Float16 half8 __attribute__((ext_vector_type(8)));
typedef _Float16 h4 __attribute__((ext_vector_type(4)));
typedef float f32x4 __attribute__((ext_vector_type(4)));
typedef int i2 __attribute__((ext_vector_type(2)));
typedef int i4 __attribute__((ext_vector_type(4)));
// Vector types get char-TBAA in clang (alias everything) -> safe for LDS type
// punning. Scalar puns (unsigned long long) carry their own TBAA tag and get
// reordered across _Float16 stores (round-2 bug) -- never use scalar puns.

__device__ __forceinline__ float rcp_f(float v) { return __builtin_amdgcn_rcpf(v); }
__device__ __forceinline__ float ex2(float v)   { return __builtin_amdgcn_exp2f(v); }

// Gate preactivations arrive PRE-SCALED: pi,pf,po = -log2e*(preact), pg = 2*log2e*(preact).
// State cs = 2*log2e * c (pre-scaled cell state).
// sigmoid(i) = 1/(1+2^pi); tanh(g) = (Eg-2)/Eg, Eg = 1+2^pg.
// cs' = cs/Ef + 2L*(Eg-2)/(Ei*Eg) -> single rcp via common denominator.
// h = (Ec-2)/(Eo*Ec), Ec = 1+2^min(cs',60)  (clamp: keeps Eo*Ec finite).
__device__ __forceinline__ float lstm_up(float pi, float pf, float pg, float po, float& cs)
{
    float ei = ex2(pi), ef = ex2(pf), eg = ex2(pg), eo = ex2(po);
    float Ei = 1.f + ei, Ef = 1.f + ef, Eg = 1.f + eg, Eo = 1.f + eo;
    float EiEg = Ei * Eg;
    float G = fmaf(2.f * LOG2E, Eg, -4.f * LOG2E);   // 2L*(Eg-2)
    float N = fmaf(cs, EiEg, Ef * G);
    cs = N * rcp_f(Ef * EiEg);
    float pc = fminf(cs, 60.f);
    float Ec = 1.f + ex2(pc);
    return (Ec - 2.f) * rcp_f(Eo * Ec);
}

// ---------------- weight prep ------------------------------------------------------------
// W1f/W1b: small-LSTM fragments as before.
// W2p: PERMUTED mid weights [16 m-tiles][16 rows][96 k] h16. m-tile p=4g+c, row m=q*4+r
// maps to original gate g, unit u = (c>=2?32:0)+(c&1)*4+8q+r. This permutation makes the
// MFMA C layout (row=q*4+r per tile) line up so each lane's lstm_up outputs ARE the next
// step's B-fragment elements: nf1[j]=unit 8q+j, nf2[j]=unit 32+8q+j.
// (Layout correctness HW-verified in round 7.)
// k: 0..31 = Wih_m cols (hs_f|hs_b), 32..95 = Whh_m cols (h2 unit = k-32).
// bzp: per-row pre-scaled bias f32 [16][16] (same permutation).
__global__ void prep_kernel(
    const float* __restrict__ Wih_f, const float* __restrict__ Whh_f,
    const float* __restrict__ bih_f, const float* __restrict__ bhh_f,
    const float* __restrict__ Wih_b, const float* __restrict__ Whh_b,
    const float* __restrict__ bih_b, const float* __restrict__ bhh_b,
    const float* __restrict__ Wih_m, const float* __restrict__ Whh_m,
    const float* __restrict__ bih_m, const float* __restrict__ bhh_m,
    h16* __restrict__ W1f, h16* __restrict__ W1b,
    h16* __restrict__ W2p, float* __restrict__ bzp)
{
    int gtid = blockIdx.x * blockDim.x + threadIdx.x;
    int gs = gridDim.x * blockDim.x;
    // small LSTMs: W1[n=64][k=32]: k<8 x, 8..23 h, 24 bias (X col24==1), 25..31 zero
    for (int idx = gtid; idx < 64 * 32; idx += gs) {
        int n = idx >> 5, k = idx & 31;
        float a = ((n >> 4) == 2) ? 2.f * LOG2E : -LOG2E;
        float vf = 0.f, vb = 0.f;
        if (k < 8)        { vf = Wih_f[n * 8 + k];       vb = Wih_b[n * 8 + k]; }
        else if (k < 24)  { vf = Whh_f[n * 16 + k - 8];  vb = Whh_b[n * 16 + k - 8]; }
        else if (k == 24) { vf = bih_f[n] + bhh_f[n];    vb = bih_b[n] + bhh_b[n]; }
        W1f[idx] = (h16)(vf * a);
        W1b[idx] = (h16)(vb * a);
    }
    // mid: permuted W2p [pm=256][k=96]
    for (int idx = gtid; idx < 256 * 96; idx += gs) {
        int pm = idx / 96, k = idx - pm * 96;
        int p = pm >> 4, m = pm & 15;
        int g = p >> 2, c = p & 3, qq = m >> 2, r = m & 3;
        int u = ((c >= 2) ? 32 : 0) + (c & 1) * 4 + 8 * qq + r;
        int n = g * 64 + u;
        float a = (g == 2) ? 2.f * LOG2E : -LOG2E;
        float v = (k < 32) ? Wih_m[n * 32 + k] : Whh_m[n * 64 + (k - 32)];
        W2p[idx] = (h16)(v * a);
    }
    // mid bias (pre-scaled, f32)
    for (int pm = gtid; pm < 256; pm += gs) {
        int p = pm >> 4, m = pm & 15;
        int g = p >> 2, c = p & 3, qq = m >> 2, r = m & 3;
        int u = ((c >= 2) ? 32 : 0) + (c & 1) * 4 + 8 * qq + r;
        int n = g * 64 + u;
        float a = (g == 2) ? 2.f * LOG2E : -LOG2E;
        bzp[pm] = (bih_m[n] + bhh_m[n]) * a;
    }
}

// ---------------- small LSTMs (fwd + bwd): ONE WAVE owns one (dir, 16-batch) recurrence ---
// v5 (kept): SWAPPED-OPERAND MFMA kills the LDS round-trip. z_g = mfma(A=W_g, B=state):
// lane(q,b) holds units q*4+r of batch b; next step's B-frag needs only a lane^16
// ds_swizzle pair. No LDS array, no barrier, no asm fence.
__global__ __launch_bounds__(256, 2) void small_lstm_kernel(
    const float* __restrict__ x,
    const float* __restrict__ h0f, const float* __restrict__ c0f,
    const float* __restrict__ h0b, const float* __restrict__ c0b,
    const h16* __restrict__ W1f, const h16* __restrict__ W1b,
    h16* __restrict__ hsf, h16* __restrict__ hsb)
{
    const int tid = threadIdx.x;
    const int wv = tid >> 6, lane = tid & 63;
    const int b = lane & 15, q = lane >> 4;

    const int wgid = blockIdx.x * 4 + wv;        // 2048 waves
    const int dir  = wgid & 1;
    const int base = (wgid >> 1) * 16;

    const float* h0 = dir ? h0b : h0f;
    const float* c0 = dir ? c0b : c0f;
    const h16* W1   = dir ? W1b : W1f;
    h16* hs = dir ? hsb : hsf;

    half8 wf0 = *(const half8*)(W1 + (0 * 16 + b) * 32 + q * 8);
    half8 wf1 = *(const half8*)(W1 + (1 * 16 + b) * 32 + q * 8);
    half8 wf2 = *(const half8*)(W1 + (2 * 16 + b) * 32 + q * 8);
    half8 wf3 = *(const half8*)(W1 + (3 * 16 + b) * 32 + q * 8);

    f32x4 cv = *(const f32x4*)(c0 + (size_t)(base + b) * 16 + q * 4);
    float cs0 = cv[0] * (2.f * LOG2E);
    float cs1 = cv[1] * (2.f * LOG2E);
    float cs2 = cv[2] * (2.f * LOG2E);
    float cs3 = cv[3] * (2.f * LOG2E);

    const int t0 = dir ? (TT - 1) : 0;

    half8 sf;
    if (q == 0) {
        const float* xp = x + ((size_t)t0 * BB + base + b) * 8;
        f32x4 u0 = *(const f32x4*)xp, u1 = *(const f32x4*)(xp + 4);
        sf[0] = (h16)u0[0]; sf[1] = (h16)u0[1]; sf[2] = (h16)u0[2]; sf[3] = (h16)u0[3];
        sf[4] = (h16)u1[0]; sf[5] = (h16)u1[1]; sf[6] = (h16)u1[2]; sf[7] = (h16)u1[3];
    } else if (q == 3) {
        sf[0] = (h16)1.f;
        sf[1] = (h16)0.f; sf[2] = (h16)0.f; sf[3] = (h16)0.f;
        sf[4] = (h16)0.f; sf[5] = (h16)0.f; sf[6] = (h16)0.f; sf[7] = (h16)0.f;
    } else {
        const float* hp = h0 + (size_t)(base + b) * 16 + (q - 1) * 8;
        f32x4 u0 = *(const f32x4*)hp, u1 = *(const f32x4*)(hp + 4);
        sf[0] = (h16)u0[0]; sf[1] = (h16)u0[1]; sf[2] = (h16)u0[2]; sf[3] = (h16)u0[3];
        sf[4] = (h16)u1[0]; sf[5] = (h16)u1[1]; sf[6] = (h16)u1[2]; sf[7] = (h16)u1[3];
    }

    // 4-slot x prefetch file (indices static under the 4x unroll -- rule #20)
    f32x4 xr[4][2];
    if (q == 0) {
#pragma unroll
        for (int u = 1; u <= 3; ++u) {
            int tl = dir ? (TT - 1 - u) : u;
            const float* xp = x + ((size_t)tl * BB + base + b) * 8;
            xr[u][0] = *(const f32x4*)xp;
            xr[u][1] = *(const f32x4*)(xp + 4);
        }
    }

    for (int it = 0; it < TT / 4; ++it) {        // 54 outer iters x 4 steps
#pragma unroll
        for (int j = 0; j < 4; ++j) {
            const int s = it * 4 + j;
            const int t = dir ? (TT - 1 - s) : s;

            f32x4 z0 = {0.f, 0.f, 0.f, 0.f}, z1 = z0, z2 = z0, z3 = z0;
            z0 = __builtin_amdgcn_mfma_f32_16x16x32_f16(wf0, sf, z0, 0, 0, 0);
            z1 = __builtin_amdgcn_mfma_f32_16x16x32_f16(wf1, sf, z1, 0, 0, 0);
            z2 = __builtin_amdgcn_mfma_f32_16x16x32_f16(wf2, sf, z2, 0, 0, 0);
            z3 = __builtin_amdgcn_mfma_f32_16x16x32_f16(wf3, sf, z3, 0, 0, 0);

            half8 xh;
            {
                const f32x4 u0 = xr[(j + 1) & 3][0], u1 = xr[(j + 1) & 3][1];
                xh[0] = (h16)u0[0]; xh[1] = (h16)u0[1]; xh[2] = (h16)u0[2]; xh[3] = (h16)u0[3];
                xh[4] = (h16)u1[0]; xh[5] = (h16)u1[1]; xh[6] = (h16)u1[2]; xh[7] = (h16)u1[3];
            }
            if (q == 0) {
                int ut = (s + 4 < TT) ? (s + 4) : (TT - 1);
                int tl = dir ? (TT - 1 - ut) : ut;
                const float* xp = x + ((size_t)tl * BB + base + b) * 8;
                xr[j][0] = *(const f32x4*)xp;
                xr[j][1] = *(const f32x4*)(xp + 4);
            }

            float hh0 = lstm_up(z0[0], z1[0], z2[0], z3[0], cs0);
            float hh1 = lstm_up(z0[1], z1[1], z2[1], z3[1], cs1);
            float hh2 = lstm_up(z0[2], z1[2], z2[2], z3[2], cs2);
            float hh3 = lstm_up(z0[3], z1[3], z2[3], z3[3], cs3);

            h4 hv;
            hv[0] = (h16)hh0; hv[1] = (h16)hh1; hv[2] = (h16)hh2; hv[3] = (h16)hh3;
            *(h4*)(hs + ((size_t)t * BB + base + b) * 16 + q * 4) = hv;

            i2 pk = __builtin_bit_cast(i2, hv);
            int sp0 = __builtin_amdgcn_ds_swizzle(pk[0], 0x401F);   // lane ^ 16
            int sp1 = __builtin_amdgcn_ds_swizzle(pk[1], 0x401F);

            i4 nw;
            nw[0] = (q == 1) ? sp0 : pk[0];
            nw[1] = (q == 1) ? sp1 : pk[1];
            nw[2] = (q == 1) ? pk[0] : sp0;
            nw[3] = (q == 1) ? pk[1] : sp1;
            half8 nf = __builtin_bit_cast(half8, nw);

            if (q == 0)      sf = xh;
            else if (q != 3) sf = nf;    // q==3 keeps its constant bias column
        }
    }
}

// ---------------- middle LSTM + dense: 4-WAVE team owns one 16-batch window -------------
// v5: same register-resident structure as v4 (2-wave, 314us) but split 4 ways -- wave ro
// owns c-block ro (m-tiles p=4g+ro): 12 MFMA + 4 lstm_up per wave-step, ~48 weight VGPR.
// Total issue unchanged; chains/SIMD double (4096 waves = 4/SIMD) in a latency-bound
// regime. Exchange: each wave writes its 8B h2-quarter, ONE barrier (double-buffered
// parity s&1, WAR-safe by the v4 argument), reads the 4 quarters: nf1=[x0,x1],
// nf2=[x2,x3]. Dense on ro==3. VGPR est ~95 < 128 cap of (256,4).
__global__ __launch_bounds__(256, 4) void mid_lstm_kernel(
    const h16* __restrict__ hsf, const h16* __restrict__ hsb,
    const float* __restrict__ h0m, const float* __restrict__ c0m,
    const h16* __restrict__ W2p, const float* __restrict__ bzp,
    const float* __restrict__ Wd, const float* __restrict__ bdp,
    float* __restrict__ out)
{
    __shared__ __attribute__((aligned(16))) i2 xch[2][4][64];   // [buf][role][lane] 8B

    const int tid = threadIdx.x;
    const int ro = tid >> 6, lane = tid & 63;
    const int b = lane & 15, q = lane >> 4;
    const int base = blockIdx.x * 16;

    // this wave's 4 m-tiles: p = 4g + ro (gate g, c-block ro)
    half8 wfr[4][3];
    f32x4 bz[4];
#pragma unroll
    for (int g = 0; g < 4; ++g) {
        int p = 4 * g + ro;
#pragma unroll
        for (int kt = 0; kt < 3; ++kt)
            wfr[g][kt] = *(const half8*)(W2p + (size_t)(p * 16 + b) * 96 + kt * 32 + q * 8);
        bz[g] = *(const f32x4*)(bzp + p * 16 + q * 4);
    }
    // dense A-frags (consumed by ro==3; row 0 = wd; permuted h2 layout is identity)
    half8 df1, df2;
#pragma unroll
    for (int j = 0; j < 8; ++j) {
        df1[j] = (b == 0) ? (h16)Wd[q * 8 + j] : (h16)0.f;
        df2[j] = (b == 0) ? (h16)Wd[32 + q * 8 + j] : (h16)0.f;
    }
    const float bdv = bdp[0];

    // cell state: cs[r] = c0m[base+b][u(ro,q,r)], u = (ro>=2?32:0)+(ro&1)*4+8q+r
    f32x4 cs;
    {
        int off = ((ro >= 2) ? 32 : 0) + (ro & 1) * 4 + 8 * q;
        f32x4 v = *(const f32x4*)(c0m + (size_t)(base + b) * 64 + off);
        cs[0] = v[0] * (2.f * LOG2E); cs[1] = v[1] * (2.f * LOG2E);
        cs[2] = v[2] * (2.f * LOG2E); cs[3] = v[3] * (2.f * LOG2E);
    }

    // initial h2 B-frags from h0m (all waves hold both)
    half8 nf1, nf2;
    {
        const float* hp = h0m + (size_t)(base + b) * 64 + q * 8;
        f32x4 a0 = *(const f32x4*)hp, a1 = *(const f32x4*)(hp + 4);
        f32x4 a2 = *(const f32x4*)(hp + 32), a3 = *(const f32x4*)(hp + 36);
        nf1[0] = (h16)a0[0]; nf1[1] = (h16)a0[1]; nf1[2] = (h16)a0[2]; nf1[3] = (h16)a0[3];
        nf1[4] = (h16)a1[0]; nf1[5] = (h16)a1[1]; nf1[6] = (h16)a1[2]; nf1[7] = (h16)a1[3];
        nf2[0] = (h16)a2[0]; nf2[1] = (h16)a2[1]; nf2[2] = (h16)a2[2]; nf2[3] = (h16)a2[3];
        nf2[4] = (h16)a3[0]; nf2[5] = (h16)a3[1]; nf2[6] = (h16)a3[2]; nf2[7] = (h16)a3[3];
    }

    // hs prefetch: lane(q,b) kt=0 element j = (q<2 ? hs_f : hs_b)[t][base+b][(q&1)*8+j]
    // (each wave loads its own copy -- same lines, same step -> L1/L2 hits)
    const h16* hsq = (q < 2) ? hsf : hsb;
    const size_t hoff = (size_t)(base + b) * 16 + (q & 1) * 8;
    uint4 hx[4];
#pragma unroll
    for (int u = 0; u < 4; ++u)
        hx[u] = *(const uint4*)(hsq + (size_t)u * BB * 16 + hoff);

    f32x4 ot;
    for (int it = 0; it < TT / 4; ++it) {        // 54 outer iters x 4 steps
#pragma unroll
        for (int j = 0; j < 4; ++j) {
            const int s = it * 4 + j;
            const half8 sf0 = __builtin_bit_cast(half8, hx[j]);   // hs(s)

            // z_g = W2p-tile(4g+ro) . [hs | h2]  (bias C-init)
            f32x4 z0 = bz[0], z1 = bz[1], z2 = bz[2], z3 = bz[3];
            z0 = __builtin_amdgcn_mfma_f32_16x16x32_f16(wfr[0][0], sf0, z0, 0, 0, 0);
            z0 = __builtin_amdgcn_mfma_f32_16x16x32_f16(wfr[0][1], nf1, z0, 0, 0, 0);
            z0 = __builtin_amdgcn_mfma_f32_16x16x32_f16(wfr[0][2], nf2, z0, 0, 0, 0);
            z1 = __builtin_amdgcn_mfma_f32_16x16x32_f16(wfr[1][0], sf0, z1, 0, 0, 0);
            z1 = __builtin_amdgcn_mfma_f32_16x16x32_f16(wfr[1][1], nf1, z1, 0, 0, 0);
            z1 = __builtin_amdgcn_mfma_f32_16x16x32_f16(wfr[1][2], nf2, z1, 0, 0, 0);
            z2 = __builtin_amdgcn_mfma_f32_16x16x32_f16(wfr[2][0], sf0, z2, 0, 0, 0);
            z2 = __builtin_amdgcn_mfma_f32_16x16x32_f16(wfr[2][1], nf1, z2, 0, 0, 0);
            z2 = __builtin_amdgcn_mfma_f32_16x16x32_f16(wfr[2][2], nf2, z2, 0, 0, 0);
            z3 = __builtin_amdgcn_mfma_f32_16x16x32_f16(wfr[3][0], sf0, z3, 0, 0, 0);
            z3 = __builtin_amdgcn_mfma_f32_16x16x32_f16(wfr[3][1], nf1, z3, 0, 0, 0);
            z3 = __builtin_amdgcn_mfma_f32_16x16x32_f16(wfr[3][2], nf2, z3, 0, 0, 0);

            // gates (i,f,g,o) = (z0,z1,z2,z3); this wave's 4 units/lane
            float c0v = cs[0];
            float hh0 = lstm_up(z0[0], z1[0], z2[0], z3[0], c0v); cs[0] = c0v;
            float c1v = cs[1];
            float hh1 = lstm_up(z0[1], z1[1], z2[1], z3[1], c1v); cs[1] = c1v;
            float c2v = cs[2];
            float hh2 = lstm_up(z0[2], z1[2], z2[2], z3[2], c2v); cs[2] = c2v;
            float c3v = cs[3];
            float hh3 = lstm_up(z0[3], z1[3], z2[3], z3[3], c3v); cs[3] = c3v;

            h4 pk;
            pk[0] = (h16)hh0; pk[1] = (h16)hh1; pk[2] = (h16)hh2; pk[3] = (h16)hh3;

            // exchange quarters (double-buffered, one barrier)
            xch[j & 1][ro][lane] = __builtin_bit_cast(i2, pk);
            // refill hs slot j for step s+4 (in flight across the barrier)
            {
                int sl = (s + 4 < TT) ? (s + 4) : (TT - 1);
                hx[j] = *(const uint4*)(hsq + (size_t)sl * BB * 16 + hoff);
            }
            __syncthreads();
            {
                i2 x0 = xch[j & 1][0][lane], x1 = xch[j & 1][1][lane];
                i2 x2 = xch[j & 1][2][lane], x3 = xch[j & 1][3][lane];
                i4 n1, n2;
                n1[0] = x0[0]; n1[1] = x0[1]; n1[2] = x1[0]; n1[3] = x1[1];
                n2[0] = x2[0]; n2[1] = x2[1]; n2[2] = x3[0]; n2[3] = x3[1];
                nf1 = __builtin_bit_cast(half8, n1);
                nf2 = __builtin_bit_cast(half8, n2);
            }

            // dense: out(s) = wd . h2(s) + bd  (ro==3; D row 0 -> q==0 lanes, elem 0)
            if (ro == 3) {
                f32x4 zd = {0.f, 0.f, 0.f, 0.f};
                zd = __builtin_amdgcn_mfma_f32_16x16x32_f16(df1, nf1, zd, 0, 0, 0);
                zd = __builtin_amdgcn_mfma_f32_16x16x32_f16(df2, nf2, zd, 0, 0, 0);
                ot[j] = zd[0] + bdv;
            }
        }
        if (ro == 3 && q == 0)
            *(f32x4*)(out + (size_t)(base + b) * TT + it * 4) = ot;
    }
}

extern "C" void kernel_launch(void* const* d_in, const int* in_sizes, int n_in,
                              void* d_out, int out_size, void* d_ws, size_t ws_size,
                              hipStream_t stream)
{
    const float* x     = (const float*)d_in[0];
    const float* h0f   = (const float*)d_in[1];
    const float* c0f   = (const float*)d_in[2];
    const float* h0b   = (const float*)d_in[3];
    const float* c0b   = (const float*)d_in[4];
    const float* h0m   = (const float*)d_in[5];
    const float* c0m   = (const float*)d_in[6];
    const float* Wih_f = (const float*)d_in[7];
    const float* Whh_f = (const float*)d_in[8];
    const float* bih_f = (const float*)d_in[9];
    const float* bhh_f = (const float*)d_in[10];
    const float* Wih_b = (const float*)d_in[11];
    const float* Whh_b = (const float*)d_in[12];
    const float* bih_b = (const float*)d_in[13];
    const float* bhh_b = (const float*)d_in[14];
    const float* Wih_m = (const float*)d_in[15];
    const float* Whh_m = (const float*)d_in[16];
    const float* bih_m = (const float*)d_in[17];
    const float* bhh_m = (const float*)d_in[18];
    const float* Wd    = (const float*)d_in[19];
    const float* bd    = (const float*)d_in[20];

    char* ws = (char*)d_ws;
    h16*   W1f = (h16*)(ws + 0);         // 64*32*2   = 4096
    h16*   W1b = (h16*)(ws + 4096);      // 4096
    h16*   W2p = (h16*)(ws + 8192);      // 256*96*2  = 49152
    float* bzp = (float*)(ws + 57344);   // 256*4     = 1024
    h16*   hsf = (h16*)(ws + 65536);                               // [T][B][16] fp16
    h16*   hsb = (h16*)(ws + 65536 + (size_t)TT * BB * 16 * 2);    // [T][B][16] fp16

    prep_kernel<<<64, 256, 0, stream>>>(Wih_f, Whh_f, bih_f, bhh_f,
                                        Wih_b, Whh_b, bih_b, bhh_b,
                                        Wih_m, Whh_m, bih_m, bhh_m,
                                        W1f, W1b, W2p, bzp);
    small_lstm_kernel<<<512, 256, 0, stream>>>(x, h0f, c0f, h0b, c0b,
                                               W1f, W1b, hsf, hsb);
    mid_lstm_kernel<<<1024, 256, 0, stream>>>(hsf, hsb, h0m, c0m, W2p, bzp,
                                              Wd, bd, (float*)d_out);
}